// Round 14
// baseline (297.283 us; speedup 1.0000x reference)
//
#include <hip/hip_runtime.h>
#include <math.h>

#define NE 64
#define NTOK 16384
#define DD 4096
#define TOPK 2
#define BLOCK 512             // 8 waves = 8 K-slices
#define TOKPB 32
#define KQN 8
#define KRANGE (DD / KQN)     // 512 k per wave
#define KC 16                 // k per chunk
#define NCH (KRANGE / KC)     // 32 chunks
#define LGSTR 68
#define PLOFF 8192            // plane dwords offset (staging [0,8192))
#define SMEM_DW (PLOFF + TOKPB * LGSTR)  // 41.5 KB

typedef __attribute__((ext_vector_type(4))) float f4x;

__device__ __forceinline__ void dma16(const float* g, float* l) {
  __builtin_amdgcn_global_load_lds(
      (const __attribute__((address_space(1))) void*)g,
      (__attribute__((address_space(3))) void*)l, 16, 0, 0);
}

#define STR2(x) #x
#define STR(x) STR2(x)

// counted wait + scheduling fence (rule #18: SB stops FMA hoisting past wait)
#define VMW(N)                                                  \
  do {                                                          \
    asm volatile("s_waitcnt vmcnt(" STR(N) ")" ::: "memory");   \
    __builtin_amdgcn_sched_barrier(0);                          \
  } while (0)

// w load: saddr(gw) + 32-bit voffset + quad imm. volatile -> program order.
#define GLD(dst, vo, IMM)                                       \
  asm volatile("global_load_dwordx4 %0, %1, %2 offset:" STR(IMM)\
               : "=&v"(dst)                                     \
               : "v"(vo), "s"(gw))

#define WLOAD(P, CB, IMM)                                       \
  do {                                                          \
    GLD(P##0, vo0 + (CB), IMM); GLD(P##1, vo1 + (CB), IMM);     \
    GLD(P##2, vo2 + (CB), IMM); GLD(P##3, vo3 + (CB), IMM);     \
    GLD(P##4, vo4 + (CB), IMM); GLD(P##5, vo5 + (CB), IMM);     \
    GLD(P##6, vo6 + (CB), IMM); GLD(P##7, vo7 + (CB), IMM);     \
  } while (0)

#define DSX(BUF, Q)                                             \
  do {                                                          \
    xv0 = *(const f4x*)(smb + bxq[Q] + (BUF) * 2048 + 0);       \
    xv1 = *(const f4x*)(smb + bxq[Q] + (BUF) * 2048 + 512);     \
    xv2 = *(const f4x*)(smb + bxq[Q] + (BUF) * 2048 + 1024);    \
    xv3 = *(const f4x*)(smb + bxq[Q] + (BUF) * 2048 + 1536);    \
  } while (0)

#define FMAJ(J, W)                                              \
  do {                                                          \
    acc[0][J] = fmaf(xv0.x, (W).x, acc[0][J]);                  \
    acc[0][J] = fmaf(xv0.y, (W).y, acc[0][J]);                  \
    acc[0][J] = fmaf(xv0.z, (W).z, acc[0][J]);                  \
    acc[0][J] = fmaf(xv0.w, (W).w, acc[0][J]);                  \
    acc[1][J] = fmaf(xv1.x, (W).x, acc[1][J]);                  \
    acc[1][J] = fmaf(xv1.y, (W).y, acc[1][J]);                  \
    acc[1][J] = fmaf(xv1.z, (W).z, acc[1][J]);                  \
    acc[1][J] = fmaf(xv1.w, (W).w, acc[1][J]);                  \
    acc[2][J] = fmaf(xv2.x, (W).x, acc[2][J]);                  \
    acc[2][J] = fmaf(xv2.y, (W).y, acc[2][J]);                  \
    acc[2][J] = fmaf(xv2.z, (W).z, acc[2][J]);                  \
    acc[2][J] = fmaf(xv2.w, (W).w, acc[2][J]);                  \
    acc[3][J] = fmaf(xv3.x, (W).x, acc[3][J]);                  \
    acc[3][J] = fmaf(xv3.y, (W).y, acc[3][J]);                  \
    acc[3][J] = fmaf(xv3.z, (W).z, acc[3][J]);                  \
    acc[3][J] = fmaf(xv3.w, (W).w, acc[3][J]);                  \
  } while (0)

#define FMA8(P)                                                 \
  do {                                                          \
    FMAJ(0, P##0); FMAJ(1, P##1); FMAJ(2, P##2); FMAJ(3, P##3); \
    FMAJ(4, P##4); FMAJ(5, P##5); FMAJ(6, P##6); FMAJ(7, P##7); \
  } while (0)

// One chunk, 6 regions. vmcnt queue annotated: Dc = this-buf DMA (in flight
// on entry), Dn = next-buf DMA. In-order vmcnt -> WLOAD(A) must precede DMA
// (extra SB enforces it).
//   S0: WLOAD(A,Q0) SB DMA | [Dc2,A8,Dn2]=12 -> vm(W0) drains Dc (buf valid)
//   S1: dsx0, WLOAD(B,Q1)  | [A8,Dn2,B8]=18 -> vm(W1) drains A
//   S2: FMA(Q0,A), dsx1, WLOAD(A,Q2) | [Dn2,B8,A8]=18 -> vm(8) drains Dn,B
//   S3: FMA(Q1,B), dsx2, WLOAD(B,Q3) | [A8,B8]=16 -> vm(8) drains A
//   S4: FMA(Q2,A), dsx3   | [B8] -> vm(0) drains B
//   S5: FMA(Q3,B)
// no-DMA chunk: W0=8, W1=8 (queues minus Dn).
#define CHUNK(BUF, CB, DMASTMT, W0, W1)                         \
  do {                                                          \
    WLOAD(wa, CB, 0);                                           \
    __builtin_amdgcn_sched_barrier(0);                          \
    DMASTMT;                                                    \
    VMW(W0);                                                    \
    DSX(BUF, 0);                                                \
    WLOAD(wb, CB, 16);                                          \
    VMW(W1);                                                    \
    FMA8(wa);                                                   \
    DSX(BUF, 1);                                                \
    WLOAD(wa, CB, 32);                                          \
    VMW(8);                                                     \
    FMA8(wb);                                                   \
    DSX(BUF, 2);                                                \
    WLOAD(wb, CB, 48);                                          \
    VMW(8);                                                     \
    FMA8(wa);                                                   \
    DSX(BUF, 3);                                                \
    VMW(0);                                                     \
    FMA8(wb);                                                   \
  } while (0)

__global__ __launch_bounds__(BLOCK) void router_kernel(
    const float* __restrict__ x, const float* __restrict__ gw,
    float* __restrict__ out, float* __restrict__ ws) {
  __shared__ __align__(16) float smem[SMEM_DW];

  const int tid = threadIdx.x;
  const int lane = tid & 63;
  const int kq = __builtin_amdgcn_readfirstlane(tid >> 6);  // K slice
  const int g = lane >> 3;  // expert sub-row: experts g + 8j
  const int s = lane & 7;   // token slot: tokens s + 8t, t=0..3
  const int tok0 = blockIdx.x * TOKPB;

  // x DMA source (per-lane, pre-swizzled; LDS dest wave-uniform+linear)
  const int swz = (lane & 3) ^ ((lane >> 3) & 3);
  const float* pgx =
      x + (size_t)(tok0 + (lane >> 2)) * DD + kq * KRANGE + swz * 4;
  const int sb = kq * 1024;  // staging dword base; buf b at +b*512

  // w byte voffsets (saddr = gw): row g+8j, col base kq*KRANGE
  const int vo0 = (g * DD + kq * KRANGE) * 4;
  const int vo1 = vo0 + 1 * 131072;
  const int vo2 = vo0 + 2 * 131072;
  const int vo3 = vo0 + 3 * 131072;
  const int vo4 = vo0 + 4 * 131072;
  const int vo5 = vo0 + 5 * 131072;
  const int vo6 = vo0 + 6 * 131072;
  const int vo7 = vo0 + 7 * 131072;

  // x LDS read byte bases per quad (conflict-free swizzle, R9-R13)
  const char* smb = (const char*)smem;
  int bxq[4];
#pragma unroll
  for (int Q = 0; Q < 4; ++Q)
    bxq[Q] = kq * 4096 + s * 64 + (((Q ^ (s >> 1)) & 3) << 4);

  float acc[4][8];
#pragma unroll
  for (int t = 0; t < 4; ++t)
#pragma unroll
    for (int j = 0; j < 8; ++j) acc[t][j] = 0.f;

  f4x wa0, wa1, wa2, wa3, wa4, wa5, wa6, wa7;
  f4x wb0, wb1, wb2, wb3, wb4, wb5, wb6, wb7;
  f4x xv0, xv1, xv2, xv3;

#define ISSUE(B, C)                                                         \
  do {                                                                      \
    dma16(pgx + (size_t)(C) * KC, &smem[sb + (B) * 512]);                   \
    dma16(pgx + (size_t)16 * DD + (size_t)(C) * KC,                         \
          &smem[sb + (B) * 512 + 256]);                                     \
  } while (0)

  ISSUE(0, 0);  // prologue: chunk 0 -> buf 0 (outstanding = [Dc2] on entry)

#pragma unroll 1
  for (int cc = 0; cc < NCH - 2; cc += 2) {
    const int cb0 = cc * 64;
    CHUNK(0, cb0, ISSUE(1, cc + 1), 10, 10);
    CHUNK(1, cb0 + 64, ISSUE(0, cc + 2), 10, 10);
  }
  {  // peeled last pair (second chunk has no next DMA -> waits shift)
    const int cb0 = (NCH - 2) * 64;
    CHUNK(0, cb0, ISSUE(1, NCH - 1), 10, 10);
    CHUNK(1, cb0 + 64, (void)0, 8, 8);
  }

  // deterministic 8-phase K-slice reduction into the single plane
  {
    float* pl = &smem[PLOFF];
#pragma unroll 1
    for (int w = 0; w < KQN; ++w) {
      if (kq == w) {
#pragma unroll
        for (int t = 0; t < 4; ++t)
#pragma unroll
          for (int j = 0; j < 8; ++j) {
            const int idx = (s + 8 * t) * LGSTR + g + 8 * j;
            if (w == 0)
              pl[idx] = acc[t][j];
            else
              pl[idx] += acc[t][j];
          }
      }
      __syncthreads();
    }
  }

  // epilogue: wave kq -> tokens kq*4..+3; lane == expert
  float psum_local = 0.f, cnt_local = 0.f;
  float* out_v = out;                // (NTOK, 2) top-k vals
  float* out_i = out + NTOK * TOPK;  // (NTOK, 2) top-k idx as float
#pragma unroll 1
  for (int ii = 0; ii < 4; ++ii) {
    const int t = kq * 4 + ii;
    float v = smem[PLOFF + t * LGSTR + lane];
    float m = v;
#pragma unroll
    for (int sh = 32; sh > 0; sh >>= 1) m = fmaxf(m, __shfl_xor(m, sh, 64));
    float ex = expf(v - m);
    float ssum = ex;
#pragma unroll
    for (int sh = 32; sh > 0; sh >>= 1) ssum += __shfl_xor(ssum, sh, 64);
    float p = ex / ssum;
    psum_local += p;

    float v1 = p; int i1 = lane;  // top-1, ties -> lowest index
#pragma unroll
    for (int sh = 32; sh > 0; sh >>= 1) {
      float ov = __shfl_xor(v1, sh, 64);
      int oi = __shfl_xor(i1, sh, 64);
      if (ov > v1 || (ov == v1 && oi < i1)) { v1 = ov; i1 = oi; }
    }
    float v2 = (lane == i1) ? -INFINITY : p; int i2 = lane;  // top-2
#pragma unroll
    for (int sh = 32; sh > 0; sh >>= 1) {
      float ov = __shfl_xor(v2, sh, 64);
      int oi = __shfl_xor(i2, sh, 64);
      if (ov > v2 || (ov == v2 && oi < i2)) { v2 = ov; i2 = oi; }
    }
    cnt_local += (lane == i1 ? 1.f : 0.f) + (lane == i2 ? 1.f : 0.f);
    if (lane == 0) {
      const int tg = tok0 + t;
      out_v[tg * 2 + 0] = v1;
      out_v[tg * 2 + 1] = v2;
      out_i[tg * 2 + 0] = (float)i1;
      out_i[tg * 2 + 1] = (float)i2;
    }
  }
  // loss partials: ws[0:64] = pick counts, ws[64:128] = prob sums
  atomicAdd(ws + lane, cnt_local);
  atomicAdd(ws + NE + lane, psum_local);
}

__global__ void loss_kernel(const float* __restrict__ ws,
                            float* __restrict__ out) {
  const int lane = threadIdx.x & 63;
  float f = ws[lane] * (1.f / (float)(NTOK * TOPK));
  float p = ws[NE + lane] * (1.f / (float)NTOK);
  float v = f * p;  // loss = E * mean_i(f_i p_i) = sum_i f_i p_i
#pragma unroll
  for (int sh = 32; sh > 0; sh >>= 1) v += __shfl_xor(v, sh, 64);
  if (lane == 0) out[NTOK * TOPK * 2] = v;
}

extern "C" void kernel_launch(void* const* d_in, const int* in_sizes, int n_in,
                              void* d_out, int out_size, void* d_ws,
                              size_t ws_size, hipStream_t stream) {
  const float* x = (const float*)d_in[0];
  const float* gw = (const float*)d_in[1];
  float* out = (float*)d_out;
  float* ws = (float*)d_ws;

  hipMemsetAsync(d_ws, 0, 2 * NE * sizeof(float), stream);
  router_kernel<<<NTOK / TOKPB, BLOCK, 0, stream>>>(x, gw, out, ws);
  loss_kernel<<<1, 64, 0, stream>>>(ws, out);
}

// Round 15
// 239.381 us; speedup vs baseline: 1.2419x; 1.2419x over previous
//
#include <hip/hip_runtime.h>
#include <math.h>

#define NE 64
#define NTOK 16384
#define DD 4096
#define TOPK 2
#define BLOCK 512            // 8 waves = 4 token-tiles x 2 expert-pairs
#define TOKPB 64
#define NSTEP (DD / 32)      // 128 K-steps of 32
#define LGSTR 68             // logit plane row stride (dwords)

using half8 = __attribute__((ext_vector_type(8))) _Float16;
using f32x4 = __attribute__((ext_vector_type(4))) float;

// Dekker split: v*64 -> hi fp16 + lo fp16 (lo = exact residual, rounded).
// Scale 64 (exact pow2) keeps lo-halves out of fp16 subnormal range for both
// x~N(0,1) and w~N(0,0.01); accumulator holds 4096*logit, unscaled exactly
// by 2^-12 in the epilogue.
__device__ __forceinline__ void split8(const f32x4 a, const f32x4 b,
                                       half8& hi, half8& lo) {
#pragma unroll
  for (int i = 0; i < 4; ++i) {
    const float v = a[i] * 64.0f;
    const _Float16 h = (_Float16)v;
    hi[i] = h;
    lo[i] = (_Float16)(v - (float)h);
  }
#pragma unroll
  for (int i = 0; i < 4; ++i) {
    const float v = b[i] * 64.0f;
    const _Float16 h = (_Float16)v;
    hi[4 + i] = h;
    lo[4 + i] = (_Float16)(v - (float)h);
  }
}

__global__ __launch_bounds__(BLOCK) void router_kernel(
    const float* __restrict__ x, const float* __restrict__ gw,
    float* __restrict__ out, float* __restrict__ ws) {
  __shared__ __align__(16) float pl[TOKPB * LGSTR];  // 17.4 KB logit plane

  const int tid = threadIdx.x;
  const int lane = tid & 63;
  const int wid = __builtin_amdgcn_readfirstlane(tid >> 6);
  const int mi = wid & 3;    // token tile (16 rows)
  const int np = wid >> 2;   // expert pair: cols np*32 .. np*32+31
  const int tok0 = blockIdx.x * TOKPB;
  const int r = lane & 15;          // row-in-tile (A) / col-in-tile (B)
  const int kg = (lane >> 4) * 8;   // per-lane k-group base within a step

  // A: lane reads x[tok0+mi*16+r][kg..kg+8) -- contiguous 8 floats per lane.
  // B: lane reads gw[np*32(+16)+r][kg..kg+8). Frag k-slot mapping cancels
  // between A and B (same bijection), so only the m/n lane mapping matters.
  const float* xp = x + (size_t)(tok0 + mi * 16 + r) * DD + kg;
  const float* b0p = gw + (size_t)(np * 32 + r) * DD + kg;
  const float* b1p = b0p + (size_t)16 * DD;

  f32x4 acc0 = {0.f, 0.f, 0.f, 0.f};
  f32x4 acc1 = {0.f, 0.f, 0.f, 0.f};

  // x prefetched 2 steps ahead (covers HBM latency); B 1 ahead (L2-hot).
  f32x4 xa0 = *(const f32x4*)(xp + 0);
  f32x4 xb0 = *(const f32x4*)(xp + 4);
  f32x4 xa1 = *(const f32x4*)(xp + 32);
  f32x4 xb1 = *(const f32x4*)(xp + 36);
  f32x4 b0a = *(const f32x4*)(b0p + 0);
  f32x4 b0b = *(const f32x4*)(b0p + 4);
  f32x4 b1a = *(const f32x4*)(b1p + 0);
  f32x4 b1b = *(const f32x4*)(b1p + 4);

#pragma unroll 1
  for (int cc = 0; cc < NSTEP; ++cc) {
    half8 Ah, Al, B0h, B0l, B1h, B1l;
    split8(xa0, xb0, Ah, Al);
    split8(b0a, b0b, B0h, B0l);
    split8(b1a, b1b, B1h, B1l);
    // rotate x pipeline, issue loads for step cc+2 (x) and cc+1 (B)
    xa0 = xa1;
    xb0 = xb1;
    if (cc + 2 < NSTEP) {
      const int ko = (cc + 2) * 32;
      xa1 = *(const f32x4*)(xp + ko);
      xb1 = *(const f32x4*)(xp + ko + 4);
    }
    if (cc + 1 < NSTEP) {
      const int ko = (cc + 1) * 32;
      b0a = *(const f32x4*)(b0p + ko);
      b0b = *(const f32x4*)(b0p + ko + 4);
      b1a = *(const f32x4*)(b1p + ko);
      b1b = *(const f32x4*)(b1p + ko + 4);
    }
    // 3-product split accumulation (small terms first)
    acc0 = __builtin_amdgcn_mfma_f32_16x16x32_f16(Al, B0h, acc0, 0, 0, 0);
    acc0 = __builtin_amdgcn_mfma_f32_16x16x32_f16(Ah, B0l, acc0, 0, 0, 0);
    acc0 = __builtin_amdgcn_mfma_f32_16x16x32_f16(Ah, B0h, acc0, 0, 0, 0);
    acc1 = __builtin_amdgcn_mfma_f32_16x16x32_f16(Al, B1h, acc1, 0, 0, 0);
    acc1 = __builtin_amdgcn_mfma_f32_16x16x32_f16(Ah, B1l, acc1, 0, 0, 0);
    acc1 = __builtin_amdgcn_mfma_f32_16x16x32_f16(Ah, B1h, acc1, 0, 0, 0);
  }

  // C layout (m89-verified, dtype-independent): col = lane&15 (expert),
  // row = (lane>>4)*4 + i (token). Unscale by 2^-12 (exact).
  {
    const int trow = (lane >> 4) * 4;
#pragma unroll
    for (int i = 0; i < 4; ++i) {
      pl[(mi * 16 + trow + i) * LGSTR + np * 32 + r] =
          acc0[i] * 2.44140625e-4f;
      pl[(mi * 16 + trow + i) * LGSTR + np * 32 + 16 + r] =
          acc1[i] * 2.44140625e-4f;
    }
  }
  __syncthreads();

  // epilogue (R8-proven): wave wid -> tokens wid*8..+7; lane == expert
  float psum_local = 0.f, cnt_local = 0.f;
  float* out_v = out;                // (NTOK, 2) top-k vals
  float* out_i = out + NTOK * TOPK;  // (NTOK, 2) top-k idx as float
#pragma unroll 1
  for (int ii = 0; ii < 8; ++ii) {
    const int t = wid * 8 + ii;
    float v = pl[t * LGSTR + lane];
    float m = v;
#pragma unroll
    for (int sh = 32; sh > 0; sh >>= 1) m = fmaxf(m, __shfl_xor(m, sh, 64));
    float ex = expf(v - m);
    float ssum = ex;
#pragma unroll
    for (int sh = 32; sh > 0; sh >>= 1) ssum += __shfl_xor(ssum, sh, 64);
    float p = ex / ssum;
    psum_local += p;

    float v1 = p; int i1 = lane;  // top-1, ties -> lowest index
#pragma unroll
    for (int sh = 32; sh > 0; sh >>= 1) {
      float ov = __shfl_xor(v1, sh, 64);
      int oi = __shfl_xor(i1, sh, 64);
      if (ov > v1 || (ov == v1 && oi < i1)) { v1 = ov; i1 = oi; }
    }
    float v2 = (lane == i1) ? -INFINITY : p; int i2 = lane;  // top-2
#pragma unroll
    for (int sh = 32; sh > 0; sh >>= 1) {
      float ov = __shfl_xor(v2, sh, 64);
      int oi = __shfl_xor(i2, sh, 64);
      if (ov > v2 || (ov == v2 && oi < i2)) { v2 = ov; i2 = oi; }
    }
    cnt_local += (lane == i1 ? 1.f : 0.f) + (lane == i2 ? 1.f : 0.f);
    if (lane == 0) {
      const int tg = tok0 + t;
      out_v[tg * 2 + 0] = v1;
      out_v[tg * 2 + 1] = v2;
      out_i[tg * 2 + 0] = (float)i1;
      out_i[tg * 2 + 1] = (float)i2;
    }
  }
  // loss partials: ws[0:64] = pick counts, ws[64:128] = prob sums
  atomicAdd(ws + lane, cnt_local);
  atomicAdd(ws + NE + lane, psum_local);
}

__global__ void loss_kernel(const float* __restrict__ ws,
                            float* __restrict__ out) {
  const int lane = threadIdx.x & 63;
  float f = ws[lane] * (1.f / (float)(NTOK * TOPK));
  float p = ws[NE + lane] * (1.f / (float)NTOK);
  float v = f * p;  // loss = E * mean_i(f_i p_i) = sum_i f_i p_i
#pragma unroll
  for (int sh = 32; sh > 0; sh >>= 1) v += __shfl_xor(v, sh, 64);
  if (lane == 0) out[NTOK * TOPK * 2] = v;
}

extern "C" void kernel_launch(void* const* d_in, const int* in_sizes, int n_in,
                              void* d_out, int out_size, void* d_ws,
                              size_t ws_size, hipStream_t stream) {
  const float* x = (const float*)d_in[0];
  const float* gw = (const float*)d_in[1];
  float* out = (float*)d_out;
  float* ws = (float*)d_ws;

  hipMemsetAsync(d_ws, 0, 2 * NE * sizeof(float), stream);
  router_kernel<<<NTOK / TOKPB, BLOCK, 0, stream>>>(x, gw, out, ws);
  loss_kernel<<<1, 64, 0, stream>>>(ws, out);
}